// Round 6
// baseline (550.345 us; speedup 1.0000x reference)
//
#include <hip/hip_runtime.h>
#include <hip/hip_bf16.h>

// Problem constants (from reference): B=32, L=8192, C=128, K=7, F=128
#define BATCH 32
#define LEN   8192
#define CDIM  128
#define TAPS  7
#define FDIM  128
#define LOUT  (LEN - TAPS + 1)   // 8186
#define BM    128                // output rows per block
#define XROWS (BM + TAPS - 1)    // 134 rows of x per block
#define NIT   (TAPS * 2 * 4)     // 56 flattened (tap, C-half, kk) steps

typedef __attribute__((ext_vector_type(8)))  short bf16x8;
typedef __attribute__((ext_vector_type(16))) float f32x16;

static __device__ __forceinline__ unsigned short bf16_rne(float f) {
    unsigned u = __float_as_uint(f);
    u += 0x7FFFu + ((u >> 16) & 1u);
    return (unsigned short)(u >> 16);
}
static __device__ __forceinline__ unsigned pack2(float a, float b) {
    return (unsigned)bf16_rne(a) | ((unsigned)bf16_rne(b) << 16);
}

// Pre-convert W fp32 [K][C][F] -> bf16 in MFMA-FRAGMENT-MAJOR order:
// wt[t][h][kk][l5][f][e], e=0..7, where c = h*64 + kk*16 + l5*8 + e.
__global__ void wconv_kernel(const float* __restrict__ w, ushort* __restrict__ wt) {
    int i = blockIdx.x * 256 + threadIdx.x;   // 7*2*4*2*128*8 = 114688 = 448*256
    int e  = i & 7;
    int f  = (i >> 3) & 127;
    int l5 = (i >> 10) & 1;
    int kk = (i >> 11) & 3;
    int h  = (i >> 13) & 1;
    int t  = i >> 14;
    int c  = h * 64 + kk * 16 + l5 * 8 + e;
    wt[i] = bf16_rne(w[(t << 14) + (c << 7) + f]);
}

// ===== REAL kernel: R5 structure (benched 105 us) + NONTEMPORAL stores =====
// out is never re-read; nt stores keep 134 MB of writes from evicting X out
// of the 256 MB L3 across graph replays. Only diff vs R5.
__global__ __launch_bounds__(256, 4)
void conv_gemm_kernel(const float* __restrict__ x, const ushort* __restrict__ wt,
                      float* __restrict__ out) {
    __shared__ __align__(16) ushort Xs[XROWS * CDIM];      // 34,304 B (X only)

    const int tid  = threadIdx.x;
    const int lane = tid & 63;
    const int wid  = tid >> 6;
    const int wm   = wid >> 1;
    const int wn   = wid & 1;
    const int l31  = lane & 31;
    const int l5   = lane >> 5;

    const int bid  = blockIdx.x;
    const int b    = bid >> 6;
    const int i0   = (bid & 63) * BM;
    const int it0  = bid % NIT;      // per-block sweep rotation (R5, kept)

    const float* xb = x + (size_t)b * LEN * CDIM;

    #pragma unroll
    for (int it = 0; it < 9; ++it) {
        int q = it * 256 + tid;
        if (q < XROWS * 16) {
            int r   = q >> 4;
            int col = q & 15;
            int gi  = i0 + r;
            float4 v0, v1;
            if (gi < LEN) {
                const float4* p = (const float4*)(xb + (size_t)gi * CDIM + col * 8);
                v0 = p[0]; v1 = p[1];
            } else {
                v0 = make_float4(0.f, 0.f, 0.f, 0.f);
                v1 = v0;
            }
            int scol = col ^ (r & 15);
            uint4 pk;
            pk.x = pack2(v0.x, v0.y);
            pk.y = pack2(v0.z, v0.w);
            pk.z = pack2(v1.x, v1.y);
            pk.w = pack2(v1.z, v1.w);
            *(uint4*)&Xs[r * CDIM + scol * 8] = pk;
        }
    }
    __syncthreads();

    f32x16 acc[2][2] = {};
    const int f0 = (wn << 6) + l31;
    const int rb = (wm << 6) + l31;
    const ushort* wlp = wt + (l5 << 10) + (f0 << 3);

    #pragma unroll
    for (int it = 0; it < NIT; ++it) {
        int s = it + it0;
        if (s >= NIT) s -= NIT;

        const int t  = s >> 3;
        const int h  = (s >> 2) & 1;
        const int kk = s & 3;
        const int jl = kk * 2 + l5;
        const int jg = h * 8 + jl;
        const int r0 = rb + t;
        const int r1 = r0 + 32;
        const ushort* wpi = wlp + s * 2048;

        bf16x8 a0 = *(const bf16x8*)&Xs[r0 * CDIM + ((jg ^ (r0 & 15)) << 3)];
        bf16x8 a1 = *(const bf16x8*)&Xs[r1 * CDIM + ((jg ^ (r1 & 15)) << 3)];
        bf16x8 b0 = *(const bf16x8*)(wpi);
        bf16x8 b1 = *(const bf16x8*)(wpi + 256);

        acc[0][0] = __builtin_amdgcn_mfma_f32_32x32x16_bf16(a0, b0, acc[0][0], 0, 0, 0);
        acc[0][1] = __builtin_amdgcn_mfma_f32_32x32x16_bf16(a0, b1, acc[0][1], 0, 0, 0);
        acc[1][0] = __builtin_amdgcn_mfma_f32_32x32x16_bf16(a1, b0, acc[1][0], 0, 0, 0);
        acc[1][1] = __builtin_amdgcn_mfma_f32_32x32x16_bf16(a1, b1, acc[1][1], 0, 0, 0);
    }

    float* ob = out + (size_t)b * LOUT * FDIM;
    #pragma unroll
    for (int fm = 0; fm < 2; ++fm) {
        #pragma unroll
        for (int fn = 0; fn < 2; ++fn) {
            #pragma unroll
            for (int r = 0; r < 16; ++r) {
                int row = (wm << 6) + (fm << 5) + (r & 3) + ((r >> 2) << 3) + (l5 << 2);
                int i = i0 + row;
                if (i < LOUT) {
                    __builtin_nontemporal_store(
                        acc[fm][fn][r],
                        &ob[(size_t)i * FDIM + (wn << 6) + (fn << 5) + l31]);
                }
            }
        }
    }
}

// ===== ABLATION probes (read-only; keep-alive prevents DCE, rule #17) =====
// MODE 0: noStore  — full pipeline, stores -> keep-alive.        ~2*(T - S)
// MODE 1: noW      — W loaded ONCE pre-loop, no per-step VMEM.   ~2*(T - W)
// MODE 2: noX      — no X global reads (synthetic stage), no st. ~2*(T - X)
// Grid 4096 (bid & 2047): ~2x duration so rows rank above the real kernel
// in the top-5 table. ABSENCE from the table => that variant fell below
// ~105 us => the removed component is the wall.
template<int MODE>
__global__ __launch_bounds__(256, 4)
void ablate(const float* __restrict__ x, const ushort* __restrict__ wt) {
    __shared__ __align__(16) ushort Xs[XROWS * CDIM];

    const int tid  = threadIdx.x;
    const int lane = tid & 63;
    const int wid  = tid >> 6;
    const int wm   = wid >> 1;
    const int wn   = wid & 1;
    const int l31  = lane & 31;
    const int l5   = lane >> 5;

    const int bid  = blockIdx.x & 2047;
    const int b    = bid >> 6;
    const int i0   = (bid & 63) * BM;
    const int it0  = bid % NIT;

    const float* xb = x + (size_t)b * LEN * CDIM;

    #pragma unroll
    for (int it = 0; it < 9; ++it) {
        int q = it * 256 + tid;
        if (q < XROWS * 16) {
            int r   = q >> 4;
            int col = q & 15;
            int gi  = i0 + r;
            float4 v0, v1;
            if (MODE == 2) {
                v0 = make_float4((float)(q & 31), 1.0f, 0.5f, 2.0f);
                v1 = v0;
            } else if (gi < LEN) {
                const float4* p = (const float4*)(xb + (size_t)gi * CDIM + col * 8);
                v0 = p[0]; v1 = p[1];
            } else {
                v0 = make_float4(0.f, 0.f, 0.f, 0.f);
                v1 = v0;
            }
            int scol = col ^ (r & 15);
            uint4 pk;
            pk.x = pack2(v0.x, v0.y);
            pk.y = pack2(v0.z, v0.w);
            pk.z = pack2(v1.x, v1.y);
            pk.w = pack2(v1.z, v1.w);
            *(uint4*)&Xs[r * CDIM + scol * 8] = pk;
        }
    }
    __syncthreads();

    f32x16 acc[2][2] = {};
    const int f0 = (wn << 6) + l31;
    const int rb = (wm << 6) + l31;
    const ushort* wlp = wt + (l5 << 10) + (f0 << 3);

    bf16x8 cb0, cb1;
    if (MODE == 1) {                 // one-shot W fragment, reused all steps
        cb0 = *(const bf16x8*)(wlp);
        cb1 = *(const bf16x8*)(wlp + 256);
    }

    #pragma unroll
    for (int it = 0; it < NIT; ++it) {
        int s = it + it0;
        if (s >= NIT) s -= NIT;

        const int t  = s >> 3;
        const int h  = (s >> 2) & 1;
        const int kk = s & 3;
        const int jl = kk * 2 + l5;
        const int jg = h * 8 + jl;
        const int r0 = rb + t;
        const int r1 = r0 + 32;

        bf16x8 a0 = *(const bf16x8*)&Xs[r0 * CDIM + ((jg ^ (r0 & 15)) << 3)];
        bf16x8 a1 = *(const bf16x8*)&Xs[r1 * CDIM + ((jg ^ (r1 & 15)) << 3)];
        bf16x8 b0, b1;
        if (MODE == 1) {
            b0 = cb0; b1 = cb1;
        } else {
            const ushort* wpi = wlp + s * 2048;
            b0 = *(const bf16x8*)(wpi);
            b1 = *(const bf16x8*)(wpi + 256);
        }

        acc[0][0] = __builtin_amdgcn_mfma_f32_32x32x16_bf16(a0, b0, acc[0][0], 0, 0, 0);
        acc[0][1] = __builtin_amdgcn_mfma_f32_32x32x16_bf16(a0, b1, acc[0][1], 0, 0, 0);
        acc[1][0] = __builtin_amdgcn_mfma_f32_32x32x16_bf16(a1, b0, acc[1][0], 0, 0, 0);
        acc[1][1] = __builtin_amdgcn_mfma_f32_32x32x16_bf16(a1, b1, acc[1][1], 0, 0, 0);
    }

    // keep-alive: element 0 of each acc chain depends on all 56 MFMAs of
    // that chain -> none of the main loop can be DCE'd; nothing is written.
    float keep = acc[0][0][0] + acc[0][1][0] + acc[1][0][0] + acc[1][1][0];
    asm volatile("" :: "v"(keep));
}

extern "C" void kernel_launch(void* const* d_in, const int* in_sizes, int n_in,
                              void* d_out, int out_size, void* d_ws, size_t ws_size,
                              hipStream_t stream) {
    const float* x = (const float*)d_in[0];   // [32, 8192, 128, 1] fp32
    const float* w = (const float*)d_in[1];   // [7, 128, 128] fp32
    float* out = (float*)d_out;               // [32, 8186, 128, 1] fp32
    ushort* wt = (ushort*)d_ws;               // 7*128*128 bf16 = 229,376 B scratch

    wconv_kernel<<<448, 256, 0, stream>>>(w, wt);
    conv_gemm_kernel<<<BATCH * 64, 256, 0, stream>>>(x, wt, out);

    // --- ablation probes (this round only; read-only, no output writes) ---
    ablate<0><<<4096, 256, 0, stream>>>(x, wt);   // noStore
    ablate<1><<<4096, 256, 0, stream>>>(x, wt);   // noW
    ablate<2><<<4096, 256, 0, stream>>>(x, wt);   // noX
}

// Round 7
// 287.991 us; speedup vs baseline: 1.9110x; 1.9110x over previous
//
#include <hip/hip_runtime.h>
#include <hip/hip_bf16.h>

// Problem constants (from reference): B=32, L=8192, C=128, K=7, F=128
#define BATCH 32
#define LEN   8192
#define CDIM  128
#define TAPS  7
#define FDIM  128
#define LOUT  (LEN - TAPS + 1)   // 8186
#define BM    128                // output rows per block
#define XROWS (BM + TAPS - 1)    // 134 rows of x per block
#define NIT   (TAPS * 2 * 4)     // 56 flattened (tap, C-half, kk) steps

typedef __attribute__((ext_vector_type(8)))  short bf16x8;
typedef __attribute__((ext_vector_type(16))) float f32x16;

static __device__ __forceinline__ unsigned short bf16_rne(float f) {
    unsigned u = __float_as_uint(f);
    u += 0x7FFFu + ((u >> 16) & 1u);
    return (unsigned short)(u >> 16);
}
static __device__ __forceinline__ unsigned pack2(float a, float b) {
    return (unsigned)bf16_rne(a) | ((unsigned)bf16_rne(b) << 16);
}

// Pre-convert W fp32 [K][C][F] -> bf16 in MFMA-FRAGMENT-MAJOR order:
// wt[t][h][kk][l5][f][e], e=0..7, where c = h*64 + kk*16 + l5*8 + e.
__global__ void wconv_kernel(const float* __restrict__ w, ushort* __restrict__ wt) {
    int i = blockIdx.x * 256 + threadIdx.x;   // 7*2*4*2*128*8 = 114688 = 448*256
    int e  = i & 7;
    int f  = (i >> 3) & 127;
    int l5 = (i >> 10) & 1;
    int kk = (i >> 11) & 3;
    int h  = (i >> 13) & 1;
    int t  = i >> 14;
    int c  = h * 64 + kk * 16 + l5 * 8 + e;
    wt[i] = bf16_rne(w[(t << 14) + (c << 7) + f]);
}

// Main fused conv-as-GEMM kernel.
// R6 ablation verdict: stores cost 48 us, PERFECTLY ADDITIVE on top of the
// 57-us read+compute phase (T_full 105 = 57 + 48) -- the [stage][compute]
// [store-burst] shape is phase-locked across blocks, so the 131 MB write
// burst overlaps nothing. THIS ROUND: split-epilogue pipeline. Pass 1
// computes the fm=0 row-half and fires its nt-stores (no dependents);
// pass 2's compute runs while those stores drain. W loads double (L2-hot,
// proven free by the noW ablate); ds_reads unchanged; reg peak drops.
__global__ __launch_bounds__(256, 4)
void conv_gemm_kernel(const float* __restrict__ x, const ushort* __restrict__ wt,
                      float* __restrict__ out) {
    __shared__ __align__(16) ushort Xs[XROWS * CDIM];      // 34,304 B (X only)

    const int tid  = threadIdx.x;
    const int lane = tid & 63;
    const int wid  = tid >> 6;       // 0..3
    const int wm   = wid >> 1;       // wave row (0..1) -> 64 rows
    const int wn   = wid & 1;        // wave col (0..1) -> 64 f
    const int l31  = lane & 31;
    const int l5   = lane >> 5;

    const int bid  = blockIdx.x;
    const int b    = bid >> 6;       // 64 row-tiles per batch
    const int i0   = (bid & 63) * BM;
    const int it0  = bid % NIT;      // per-block sweep rotation (R5, kept: -4%)

    const float* xb = x + (size_t)b * LEN * CDIM;

    // ---- Stage X window: fp32 global -> bf16 LDS, swizzled (col ^= row&15) ----
    #pragma unroll
    for (int it = 0; it < 9; ++it) {
        int q = it * 256 + tid;
        if (q < XROWS * 16) {
            int r   = q >> 4;
            int col = q & 15;
            int gi  = i0 + r;
            float4 v0, v1;
            if (gi < LEN) {
                const float4* p = (const float4*)(xb + (size_t)gi * CDIM + col * 8);
                v0 = p[0]; v1 = p[1];
            } else {
                v0 = make_float4(0.f, 0.f, 0.f, 0.f);
                v1 = v0;
            }
            int scol = col ^ (r & 15);
            uint4 pk;
            pk.x = pack2(v0.x, v0.y);
            pk.y = pack2(v0.z, v0.w);
            pk.z = pack2(v1.x, v1.y);
            pk.w = pack2(v1.z, v1.w);
            *(uint4*)&Xs[r * CDIM + scol * 8] = pk;
        }
    }
    __syncthreads();                 // the ONLY barrier

    const int f0 = (wn << 6) + l31;
    const int rb = (wm << 6) + l31;  // fragment row base (+t per tap)
    const ushort* wlp = wt + (l5 << 10) + (f0 << 3);
    float* ob = out + (size_t)b * LOUT * FDIM;

    // ---- Two row-half passes: compute fm-half, fire its stores, move on ----
    #pragma unroll
    for (int pass = 0; pass < 2; ++pass) {
        f32x16 acc[2] = {};          // [fn] for this row-half only (32 AGPR)
        const int rbp = rb + (pass << 5);    // +0 or +32 rows

        #pragma unroll 8
        for (int it = 0; it < NIT; ++it) {
            int s = it + it0;
            if (s >= NIT) s -= NIT;  // rotated step index

            const int t  = s >> 3;           // tap
            const int h  = (s >> 2) & 1;     // C-half
            const int kk = s & 3;
            const int jl = kk * 2 + l5;      // 0..7 within the C-half
            const int jg = h * 8 + jl;       // 0..15 within the full row
            const int r  = rbp + t;
            const ushort* wpi = wlp + s * 2048;

            bf16x8 a  = *(const bf16x8*)&Xs[r * CDIM + ((jg ^ (r & 15)) << 3)];
            bf16x8 b0 = *(const bf16x8*)(wpi);
            bf16x8 b1 = *(const bf16x8*)(wpi + 256);   // f0 + 32

            acc[0] = __builtin_amdgcn_mfma_f32_32x32x16_bf16(a, b0, acc[0], 0, 0, 0);
            acc[1] = __builtin_amdgcn_mfma_f32_32x32x16_bf16(a, b1, acc[1], 0, 0, 0);
        }

        // ---- Fire this half's stores (nontemporal, no dependents) ----
        // C/D layout: col=lane&31, row=(reg&3)+8*(reg>>2)+4*(lane>>5)
        #pragma unroll
        for (int fn = 0; fn < 2; ++fn) {
            #pragma unroll
            for (int r = 0; r < 16; ++r) {
                int row = (wm << 6) + (pass << 5)
                        + (r & 3) + ((r >> 2) << 3) + (l5 << 2);
                int i = i0 + row;
                if (i < LOUT) {
                    __builtin_nontemporal_store(
                        acc[fn][r],
                        &ob[(size_t)i * FDIM + (wn << 6) + (fn << 5) + l31]);
                }
            }
        }
        // Pin: pass-1 stores must issue BEFORE pass-2's loop body so their
        // drain overlaps pass-2 compute (they have no dependents; the wave
        // does not wait on them).
        if (pass == 0) __builtin_amdgcn_sched_barrier(0);
    }
}

extern "C" void kernel_launch(void* const* d_in, const int* in_sizes, int n_in,
                              void* d_out, int out_size, void* d_ws, size_t ws_size,
                              hipStream_t stream) {
    const float* x = (const float*)d_in[0];   // [32, 8192, 128, 1] fp32
    const float* w = (const float*)d_in[1];   // [7, 128, 128] fp32
    float* out = (float*)d_out;               // [32, 8186, 128, 1] fp32
    ushort* wt = (ushort*)d_ws;               // 7*128*128 bf16 = 229,376 B scratch

    wconv_kernel<<<448, 256, 0, stream>>>(w, wt);
    conv_gemm_kernel<<<BATCH * 64, 256, 0, stream>>>(x, wt, out);
}